// Round 1
// baseline (38.234 us; speedup 1.0000x reference)
//
#include <hip/hip_runtime.h>

#define DEGREE 32
#define DIMS 8
#define NB 32
#define NPOS 65536

__global__ __launch_bounds__(256) void basis_kernel(
    const float* __restrict__ weights,    // (B, DIMS, DEGREE)
    const float* __restrict__ positions,  // (B, N)
    float* __restrict__ out,              // (B, N, DIMS)
    float* __restrict__ out_zero)         // (B, N, DIMS) -> all zeros
{
    __shared__ float wT[DEGREE][DIMS];    // weights transposed to [g][d]

    const int b    = blockIdx.x >> 8;     // 256 blocks per batch
    const int nblk = blockIdx.x & 255;
    const int tid  = threadIdx.x;

    // Stage this batch's weights into LDS, transposed. tid = d*32 + g.
    {
        const float* wb = weights + b * (DIMS * DEGREE);
        float v = wb[tid];
        int d = tid >> 5;
        int g = tid & 31;
        wT[g][d] = v;
    }
    __syncthreads();

    const int n = nblk * 256 + tid;
    const float x = positions[b * NPOS + n];

    float acc[DIMS];
    #pragma unroll
    for (int d = 0; d < DIMS; ++d) acc[d] = 0.0f;

    const float kscale = -12.5f;            // -1/(2*0.04)
    const float cstep  = 1.01f / 31.0f;     // linspace(0, 1.01, 32) step

    #pragma unroll 4
    for (int g = 0; g < DEGREE; ++g) {
        float c    = cstep * (float)g;
        float diff = x - c;
        float e    = __expf(diff * diff * kscale);
        float4 w0 = *reinterpret_cast<const float4*>(&wT[g][0]);
        float4 w1 = *reinterpret_cast<const float4*>(&wT[g][4]);
        acc[0] = fmaf(e, w0.x, acc[0]);
        acc[1] = fmaf(e, w0.y, acc[1]);
        acc[2] = fmaf(e, w0.z, acc[2]);
        acc[3] = fmaf(e, w0.w, acc[3]);
        acc[4] = fmaf(e, w1.x, acc[4]);
        acc[5] = fmaf(e, w1.y, acc[5]);
        acc[6] = fmaf(e, w1.z, acc[6]);
        acc[7] = fmaf(e, w1.w, acc[7]);
    }

    const size_t base = (size_t)(b * NPOS + n) * DIMS;
    float4* o = reinterpret_cast<float4*>(out + base);
    o[0] = make_float4(acc[0], acc[1], acc[2], acc[3]);
    o[1] = make_float4(acc[4], acc[5], acc[6], acc[7]);
    float4* z = reinterpret_cast<float4*>(out_zero + base);
    z[0] = make_float4(0.0f, 0.0f, 0.0f, 0.0f);
    z[1] = make_float4(0.0f, 0.0f, 0.0f, 0.0f);
}

extern "C" void kernel_launch(void* const* d_in, const int* in_sizes, int n_in,
                              void* d_out, int out_size, void* d_ws, size_t ws_size,
                              hipStream_t stream) {
    const float* weights   = (const float*)d_in[0];
    // d_in[1] = weights_std: unused (second output is exactly zeros)
    const float* positions = (const float*)d_in[2];

    float* out      = (float*)d_out;
    float* out_zero = out + (size_t)NB * NPOS * DIMS;

    dim3 grid(NB * 256);
    dim3 block(256);
    basis_kernel<<<grid, block, 0, stream>>>(weights, positions, out, out_zero);
}

// Round 2
// 32.762 us; speedup vs baseline: 1.1670x; 1.1670x over previous
//
#include <hip/hip_runtime.h>

#define DEGREE 32
#define DIMS 8
#define NB 32
#define NPOS 65536

// exp(-(d*d)/(2*0.04)) = exp2( d*d * (-12.5 * log2(e)) )
#define K_EXP2 (-18.033688011112043f)
#define CSTEP  (1.01f / 31.0f)

__global__ __launch_bounds__(256) void basis_kernel(
    const float* __restrict__ weights,    // (B, DIMS, DEGREE)
    const float* __restrict__ positions,  // (B, N)
    float* __restrict__ out,              // (B, N, DIMS)
    float* __restrict__ out_zero)         // (B, N, DIMS) -> all zeros
{
    const int b    = blockIdx.x >> 8;     // 256 blocks per batch
    const int nblk = blockIdx.x & 255;
    const int tid  = threadIdx.x;

    // Wave-uniform base: compiler should select s_load (SGPR weights).
    const float* __restrict__ wb = weights + b * (DIMS * DEGREE);

    const int n = nblk * 256 + tid;
    const float x = positions[b * NPOS + n];

    float acc[DIMS];
    #pragma unroll
    for (int d = 0; d < DIMS; ++d) acc[d] = 0.0f;

    float c = 0.0f;
    #pragma unroll 4
    for (int g = 0; g < DEGREE; ++g) {
        float diff = x - c;
        float e    = __builtin_amdgcn_exp2f(diff * diff * K_EXP2);
        c += CSTEP;
        #pragma unroll
        for (int d = 0; d < DIMS; ++d) {
            acc[d] = fmaf(e, wb[d * DEGREE + g], acc[d]);  // uniform weight index
        }
    }

    const size_t base = (size_t)(b * NPOS + n) * DIMS;
    float4* o = reinterpret_cast<float4*>(out + base);
    o[0] = make_float4(acc[0], acc[1], acc[2], acc[3]);
    o[1] = make_float4(acc[4], acc[5], acc[6], acc[7]);
    float4* z = reinterpret_cast<float4*>(out_zero + base);
    z[0] = make_float4(0.0f, 0.0f, 0.0f, 0.0f);
    z[1] = make_float4(0.0f, 0.0f, 0.0f, 0.0f);
}

extern "C" void kernel_launch(void* const* d_in, const int* in_sizes, int n_in,
                              void* d_out, int out_size, void* d_ws, size_t ws_size,
                              hipStream_t stream) {
    const float* weights   = (const float*)d_in[0];
    // d_in[1] = weights_std: unused (second output is exactly zeros)
    const float* positions = (const float*)d_in[2];

    float* out      = (float*)d_out;
    float* out_zero = out + (size_t)NB * NPOS * DIMS;

    dim3 grid(NB * 256);
    dim3 block(256);
    basis_kernel<<<grid, block, 0, stream>>>(weights, positions, out, out_zero);
}